// Round 1
// baseline (677.092 us; speedup 1.0000x reference)
//
#include <hip/hip_runtime.h>
#include <hip/hip_bf16.h>
#include <stdint.h>

// ---------- types ----------
typedef __bf16 bf16_t;
typedef __attribute__((ext_vector_type(8))) __bf16 bf16x8;   // MFMA A/B frag (4 VGPR)
typedef __attribute__((ext_vector_type(4))) float floatx4;   // MFMA C/D frag

typedef __attribute__((address_space(1))) const unsigned int gu32_t;
typedef __attribute__((address_space(3))) unsigned int lu32_t;

// async global->LDS, 16B per lane; LDS dest = wave-uniform base + lane*16
__device__ __forceinline__ void async16(const void* g, void* l) {
    __builtin_amdgcn_global_load_lds((gu32_t*)g, (lu32_t*)l, 16, 0, 0);
}

// ---------- fp32 -> bf16 convert ----------
__global__ __launch_bounds__(256) void cvt_f32_bf16(const float* __restrict__ in,
                                                    bf16_t* __restrict__ out) {
    int i = (blockIdx.x * 256 + threadIdx.x) * 8;
    float4 a = *(const float4*)(in + i);
    float4 b = *(const float4*)(in + i + 4);
    bf16x8 v;
    v[0] = (bf16_t)a.x; v[1] = (bf16_t)a.y; v[2] = (bf16_t)a.z; v[3] = (bf16_t)a.w;
    v[4] = (bf16_t)b.x; v[5] = (bf16_t)b.y; v[6] = (bf16_t)b.z; v[7] = (bf16_t)b.w;
    *(bf16x8*)(out + i) = v;
}

// ---------- GEMM: C[m,n] = sum_k A[m,k]*B[n,k] + bias ----------
// A: MxK row-major bf16, B: NxK row-major bf16 (i.e. x @ W.T with W[out,in]).
// 128x128 tile, BK=64, 256 threads (4 waves, each 64x64 = 4x4 of 16x16 mfma).
template <bool OUT_F32, bool BIAS_ROW>
__global__ __launch_bounds__(256) void gemm_bt(const bf16_t* __restrict__ A,
                                               const bf16_t* __restrict__ B,
                                               const float* __restrict__ bias,
                                               float* __restrict__ Cf,
                                               bf16_t* __restrict__ Cb,
                                               int M, int N, int K) {
    __shared__ bf16_t As[128 * 64];
    __shared__ bf16_t Bs[128 * 64];
    const int tid = threadIdx.x;
    const int wave = tid >> 6, lane = tid & 63;
    const int quad = lane >> 4, l16 = lane & 15;
    const int wm = (wave >> 1) * 64, wn = (wave & 1) * 64;
    const int tm = blockIdx.x * 128, tn = blockIdx.y * 128;

    floatx4 acc[4][4];
#pragma unroll
    for (int i = 0; i < 4; ++i)
#pragma unroll
        for (int j = 0; j < 4; ++j) acc[i][j] = floatx4{0.f, 0.f, 0.f, 0.f};

    const bf16_t* Abase = A + tm * K;
    const bf16_t* Bbase = B + tn * K;

    for (int kk = 0; kk < K; kk += 64) {
        // stage 128x64 bf16 tiles: 1024 chunks of 8 bf16, 4 per thread
#pragma unroll
        for (int it = 0; it < 4; ++it) {
            int chunk = it * 256 + tid;
            int r = chunk >> 3, c = chunk & 7;
            async16(Abase + r * K + kk + c * 8, As + (it * 256 + wave * 64) * 8);
            async16(Bbase + r * K + kk + c * 8, Bs + (it * 256 + wave * 64) * 8);
        }
        __syncthreads();
#pragma unroll
        for (int ks = 0; ks < 2; ++ks) {
            bf16x8 af[4], bf[4];
#pragma unroll
            for (int mt = 0; mt < 4; ++mt)
                af[mt] = *(const bf16x8*)(As + (wm + mt * 16 + l16) * 64 + ks * 32 + quad * 8);
#pragma unroll
            for (int nt = 0; nt < 4; ++nt)
                bf[nt] = *(const bf16x8*)(Bs + (wn + nt * 16 + l16) * 64 + ks * 32 + quad * 8);
#pragma unroll
            for (int mt = 0; mt < 4; ++mt)
#pragma unroll
                for (int nt = 0; nt < 4; ++nt)
                    acc[mt][nt] = __builtin_amdgcn_mfma_f32_16x16x32_bf16(af[mt], bf[nt],
                                                                          acc[mt][nt], 0, 0, 0);
        }
        __syncthreads();
    }
    // epilogue: C/D layout col=lane&15, row=quad*4+reg
#pragma unroll
    for (int mt = 0; mt < 4; ++mt)
#pragma unroll
        for (int nt = 0; nt < 4; ++nt)
#pragma unroll
            for (int r = 0; r < 4; ++r) {
                int row = tm + wm + mt * 16 + quad * 4 + r;
                int col = tn + wn + nt * 16 + l16;
                float bv = BIAS_ROW ? bias[row] : bias[col];
                float v = acc[mt][nt][r] + bv;
                if (OUT_F32) Cf[row * N + col] = v;
                else Cb[row * N + col] = (bf16_t)v;
            }
}

// ---------- flash attention (no mask), bf16, online softmax ----------
// Q,K: [B*S][2048] (head h at cols h*128..), Vt: [2048 feat][B*S tokens].
// grid (S/64, H, B), 256 threads. Wave w owns q-rows [16w,16w+16).
__global__ __launch_bounds__(256) void flash_attn(const bf16_t* __restrict__ Q,
                                                  const bf16_t* __restrict__ Kp,
                                                  const bf16_t* __restrict__ Vt,
                                                  bf16_t* __restrict__ O) {
    __shared__ bf16_t Qs[64 * 128];
    __shared__ bf16_t Ks[64 * 128];
    __shared__ bf16_t Vts[128 * 64];  // [d][key] for this tile
    __shared__ bf16_t Ps[64 * 64];
    const int tid = threadIdx.x;
    const int wave = tid >> 6, lane = tid & 63;
    const int quad = lane >> 4, l16 = lane & 15;
    const int HID = 2048, S = 2048;
    const float SL2E = 0.088388347688f * 1.44269504089f;  // log2(e)/sqrt(128)

    const int qrow0 = blockIdx.z * S + blockIdx.x * 64;
    const int krow0 = blockIdx.z * S;
    const int hoff = blockIdx.y * 128;

    // stage Q tile 64x128 (persist whole kernel)
#pragma unroll
    for (int it = 0; it < 4; ++it) {
        int chunk = it * 256 + tid;
        int r = chunk >> 4, c = chunk & 15;
        async16(Q + (qrow0 + r) * HID + hoff + c * 8, Qs + (it * 256 + wave * 64) * 8);
    }

    float m_i[4], l_i[4];
    floatx4 Oacc[8];
#pragma unroll
    for (int r = 0; r < 4; ++r) { m_i[r] = -3.0e38f; l_i[r] = 0.f; }
#pragma unroll
    for (int dt = 0; dt < 8; ++dt) Oacc[dt] = floatx4{0.f, 0.f, 0.f, 0.f};

    for (int kt = 0; kt < 32; ++kt) {
        int kb = krow0 + kt * 64;
        // K tile 64 keys x 128 d
#pragma unroll
        for (int it = 0; it < 4; ++it) {
            int chunk = it * 256 + tid;
            int r = chunk >> 4, c = chunk & 15;
            async16(Kp + (kb + r) * HID + hoff + c * 8, Ks + (it * 256 + wave * 64) * 8);
        }
        // Vt tile 128 d x 64 keys (global already transposed)
#pragma unroll
        for (int it = 0; it < 4; ++it) {
            int chunk = it * 256 + tid;
            int r = chunk >> 3, c = chunk & 7;
            async16(Vt + (hoff + r) * 2 * S + kb + c * 8, Vts + (it * 256 + wave * 64) * 8);
        }
        __syncthreads();

        // S = Q K^T  (16x64 per wave)
        floatx4 sf[4];
#pragma unroll
        for (int nt = 0; nt < 4; ++nt) sf[nt] = floatx4{0.f, 0.f, 0.f, 0.f};
#pragma unroll
        for (int ks = 0; ks < 4; ++ks) {
            bf16x8 a = *(const bf16x8*)(Qs + (wave * 16 + l16) * 128 + ks * 32 + quad * 8);
#pragma unroll
            for (int nt = 0; nt < 4; ++nt) {
                bf16x8 b = *(const bf16x8*)(Ks + (nt * 16 + l16) * 128 + ks * 32 + quad * 8);
                sf[nt] = __builtin_amdgcn_mfma_f32_16x16x32_bf16(a, b, sf[nt], 0, 0, 0);
            }
        }
        // online softmax in log2 domain
        float alpha[4], rowsum[4];
#pragma unroll
        for (int r = 0; r < 4; ++r) {
            float mx = -3.0e38f;
#pragma unroll
            for (int nt = 0; nt < 4; ++nt) mx = fmaxf(mx, sf[nt][r]);
            mx *= SL2E;
#pragma unroll
            for (int sh = 1; sh < 16; sh <<= 1) mx = fmaxf(mx, __shfl_xor(mx, sh));
            float mnew = fmaxf(m_i[r], mx);
            alpha[r] = exp2f(m_i[r] - mnew);
            m_i[r] = mnew;
            rowsum[r] = 0.f;
        }
#pragma unroll
        for (int nt = 0; nt < 4; ++nt)
#pragma unroll
            for (int r = 0; r < 4; ++r) {
                float p = exp2f(sf[nt][r] * SL2E - m_i[r]);
                rowsum[r] += p;
                Ps[(wave * 16 + quad * 4 + r) * 64 + nt * 16 + l16] = (bf16_t)p;
            }
#pragma unroll
        for (int r = 0; r < 4; ++r) {
            float s = rowsum[r];
#pragma unroll
            for (int sh = 1; sh < 16; sh <<= 1) s += __shfl_xor(s, sh);
            l_i[r] = l_i[r] * alpha[r] + s;
        }
#pragma unroll
        for (int dt = 0; dt < 8; ++dt)
#pragma unroll
            for (int r = 0; r < 4; ++r) Oacc[dt][r] *= alpha[r];

        // O += P V   (Ps rows are wave-private; compiler handles lgkmcnt)
#pragma unroll
        for (int ks = 0; ks < 2; ++ks) {
            bf16x8 a = *(const bf16x8*)(Ps + (wave * 16 + l16) * 64 + ks * 32 + quad * 8);
#pragma unroll
            for (int dt = 0; dt < 8; ++dt) {
                bf16x8 b = *(const bf16x8*)(Vts + (dt * 16 + l16) * 64 + ks * 32 + quad * 8);
                Oacc[dt] = __builtin_amdgcn_mfma_f32_16x16x32_bf16(a, b, Oacc[dt], 0, 0, 0);
            }
        }
        __syncthreads();  // protect Ks/Vts before next restage
    }
    // epilogue: O / l
#pragma unroll
    for (int r = 0; r < 4; ++r) l_i[r] = 1.0f / l_i[r];
#pragma unroll
    for (int dt = 0; dt < 8; ++dt)
#pragma unroll
        for (int r = 0; r < 4; ++r) {
            int row = qrow0 + wave * 16 + quad * 4 + r;
            int col = hoff + dt * 16 + l16;
            O[row * HID + col] = (bf16_t)(Oacc[dt][r] * l_i[r]);
        }
}

// ---------- launch ----------
extern "C" void kernel_launch(void* const* d_in, const int* in_sizes, int n_in,
                              void* d_out, int out_size, void* d_ws, size_t ws_size,
                              hipStream_t stream) {
    const float* x  = (const float*)d_in[0];
    const float* Wq = (const float*)d_in[1];
    const float* bq = (const float*)d_in[2];
    const float* Wk = (const float*)d_in[3];
    const float* bk = (const float*)d_in[4];
    const float* Wv = (const float*)d_in[5];
    const float* bv = (const float*)d_in[6];
    const float* Wo = (const float*)d_in[7];
    const float* bo = (const float*)d_in[8];
    float* out = (float*)d_out;

    const int T = 4096;          // B*S tokens
    const int H = 2048;          // hidden
    bf16_t* ws  = (bf16_t*)d_ws;
    bf16_t* xb  = ws;             // T*H
    bf16_t* wqb = xb  + T * H;    // H*H
    bf16_t* wkb = wqb + H * H;
    bf16_t* wvb = wkb + H * H;
    bf16_t* wob = wvb + H * H;
    bf16_t* Qb  = wob + H * H;    // T*H
    bf16_t* Kb  = Qb  + T * H;
    bf16_t* Vtb = Kb  + T * H;    // H x T  (V transposed: feature-major)
    bf16_t* Ab  = Vtb + T * H;    // T*H attention context
    size_t need = (size_t)(Ab + T * H - ws) * sizeof(bf16_t);
    if (ws_size < need) return;  // fail loudly rather than corrupt

    cvt_f32_bf16<<<T * H / 2048, 256, 0, stream>>>(x, xb);
    cvt_f32_bf16<<<H * H / 2048, 256, 0, stream>>>(Wq, wqb);
    cvt_f32_bf16<<<H * H / 2048, 256, 0, stream>>>(Wk, wkb);
    cvt_f32_bf16<<<H * H / 2048, 256, 0, stream>>>(Wv, wvb);
    cvt_f32_bf16<<<H * H / 2048, 256, 0, stream>>>(Wo, wob);

    dim3 gq(T / 128, H / 128);   // (32,16)
    gemm_bt<false, false><<<gq, 256, 0, stream>>>(xb, wqb, bq, nullptr, Qb, T, H, H);
    gemm_bt<false, false><<<gq, 256, 0, stream>>>(xb, wkb, bk, nullptr, Kb, T, H, H);
    // V^T = Wv * x^T : swap operands, bias per row (feature)
    dim3 gv(H / 128, T / 128);   // (16,32)
    gemm_bt<false, true><<<gv, 256, 0, stream>>>(wvb, xb, bv, nullptr, Vtb, H, T, H);

    flash_attn<<<dim3(32, 16, 2), 256, 0, stream>>>(Qb, Kb, Vtb, Ab);

    gemm_bt<true, false><<<gq, 256, 0, stream>>>(Ab, wob, bo, out, nullptr, T, H, H);
}

// Round 2
// 461.054 us; speedup vs baseline: 1.4686x; 1.4686x over previous
//
#include <hip/hip_runtime.h>
#include <hip/hip_bf16.h>
#include <stdint.h>

// ---------- types ----------
typedef __bf16 bf16_t;
typedef __attribute__((ext_vector_type(8))) __bf16 bf16x8;   // MFMA A/B frag (4 VGPR)
typedef __attribute__((ext_vector_type(4))) float floatx4;   // MFMA C/D frag

typedef __attribute__((address_space(1))) const unsigned int gu32_t;
typedef __attribute__((address_space(3))) unsigned int lu32_t;

// async global->LDS, 16B per lane; LDS dest = wave-uniform base + lane*16
__device__ __forceinline__ void async16(const void* g, void* l) {
    __builtin_amdgcn_global_load_lds((gu32_t*)g, (lu32_t*)l, 16, 0, 0);
}

__device__ __forceinline__ uint32_t pack2(float lo, float hi) {
    union { bf16_t h[2]; uint32_t u; } cv;
    cv.h[0] = (bf16_t)lo; cv.h[1] = (bf16_t)hi;
    return cv.u;
}

// ---------- fp32 -> bf16 convert ----------
__global__ __launch_bounds__(256) void cvt_f32_bf16(const float* __restrict__ in,
                                                    bf16_t* __restrict__ out) {
    int i = (blockIdx.x * 256 + threadIdx.x) * 8;
    float4 a = *(const float4*)(in + i);
    float4 b = *(const float4*)(in + i + 4);
    bf16x8 v;
    v[0] = (bf16_t)a.x; v[1] = (bf16_t)a.y; v[2] = (bf16_t)a.z; v[3] = (bf16_t)a.w;
    v[4] = (bf16_t)b.x; v[5] = (bf16_t)b.y; v[6] = (bf16_t)b.z; v[7] = (bf16_t)b.w;
    *(bf16x8*)(out + i) = v;
}

// ---------- GEMM: C[m,n] = sum_k A[m,k]*B[n,k] + bias ----------
// A: MxK row-major bf16, B: NxK row-major bf16. 128x128 tile, BK=64, 4 waves.
// LDS tiles are XOR-swizzled: LDS chunk (r,c') holds global chunk (r, c'^(r&7)).
// Staging permutes the GLOBAL source address (global_load_lds dest must stay
// contiguous); fragment reads then spread across all 32 banks (<=2-way).
// Column bias may be split at `nsplit` (merged Q|K projection).
template <bool OUT_F32, bool BIAS_ROW>
__global__ __launch_bounds__(256) void gemm_bt(const bf16_t* __restrict__ A,
                                               const bf16_t* __restrict__ B,
                                               const float* __restrict__ bias,
                                               const float* __restrict__ bias2,
                                               int nsplit,
                                               float* __restrict__ Cf,
                                               bf16_t* __restrict__ Cb,
                                               int M, int N, int K, int ldc) {
    __shared__ bf16_t As[128 * 64];
    __shared__ bf16_t Bs[128 * 64];
    const int tid = threadIdx.x;
    const int wave = tid >> 6, lane = tid & 63;
    const int quad = lane >> 4, l16 = lane & 15;
    const int wm = (wave >> 1) * 64, wn = (wave & 1) * 64;
    const int tm = blockIdx.x * 128, tn = blockIdx.y * 128;

    floatx4 acc[4][4];
#pragma unroll
    for (int i = 0; i < 4; ++i)
#pragma unroll
        for (int j = 0; j < 4; ++j) acc[i][j] = floatx4{0.f, 0.f, 0.f, 0.f};

    const bf16_t* Abase = A + (size_t)tm * K;
    const bf16_t* Bbase = B + (size_t)tn * K;
    const int sw = l16 & 7;  // row&7 for all fragment rows (wm/mt multiples of 8)

    for (int kk = 0; kk < K; kk += 64) {
        // stage 128x64 tiles: 1024 chunks of 16B, 4 per thread, source-swizzled
#pragma unroll
        for (int it = 0; it < 4; ++it) {
            int chunk = it * 256 + tid;
            int r = chunk >> 3, c = chunk & 7;
            int c2 = c ^ (r & 7);
            async16(Abase + r * K + kk + c2 * 8, As + (it * 256 + wave * 64) * 8);
            async16(Bbase + r * K + kk + c2 * 8, Bs + (it * 256 + wave * 64) * 8);
        }
        __syncthreads();
#pragma unroll
        for (int ks = 0; ks < 2; ++ks) {
            bf16x8 af[4], bf[4];
#pragma unroll
            for (int mt = 0; mt < 4; ++mt)
                af[mt] = *(const bf16x8*)(As + (wm + mt * 16 + l16) * 64 +
                                          ((ks * 4 + quad) ^ sw) * 8);
#pragma unroll
            for (int nt = 0; nt < 4; ++nt)
                bf[nt] = *(const bf16x8*)(Bs + (wn + nt * 16 + l16) * 64 +
                                          ((ks * 4 + quad) ^ sw) * 8);
#pragma unroll
            for (int mt = 0; mt < 4; ++mt)
#pragma unroll
                for (int nt = 0; nt < 4; ++nt)
                    acc[mt][nt] = __builtin_amdgcn_mfma_f32_16x16x32_bf16(af[mt], bf[nt],
                                                                          acc[mt][nt], 0, 0, 0);
        }
        __syncthreads();
    }
    // epilogue: C/D layout col=lane&15, row=quad*4+reg
#pragma unroll
    for (int mt = 0; mt < 4; ++mt)
#pragma unroll
        for (int nt = 0; nt < 4; ++nt)
#pragma unroll
            for (int r = 0; r < 4; ++r) {
                int row = tm + wm + mt * 16 + quad * 4 + r;
                int col = tn + wn + nt * 16 + l16;
                float bv = BIAS_ROW ? bias[row]
                                    : (col < nsplit ? bias[col] : bias2[col - nsplit]);
                float v = acc[mt][nt][r] + bv;
                if (OUT_F32) Cf[(size_t)row * ldc + col] = v;
                else Cb[(size_t)row * ldc + col] = (bf16_t)v;
            }
}

// ---------- flash attention (no mask), bf16, online softmax ----------
// Computes S^T = K Q^T per tile (C-layout: row=key, col=q) so P already lives
// in the q=l16 lane column; the C->A layout transform for PV is a pure
// in-register lane exchange (no Ps LDS round-trip). Q fragments are
// loop-invariant and preloaded from global. Ks/Vts XOR-swizzled as in gemm_bt.
// LDS = 32 KB -> 5 blocks/CU by LDS; launch_bounds(256,4) -> 4 blocks/CU.
// Q,K: [T][4096] halves of merged QK buffer; Vt: [2048][T]; O: [T][2048].
__global__ __launch_bounds__(256, 4) void flash_attn(const bf16_t* __restrict__ Qp,
                                                     const bf16_t* __restrict__ Kp,
                                                     const bf16_t* __restrict__ Vt,
                                                     bf16_t* __restrict__ O) {
    __shared__ bf16_t Ks[64 * 128];
    __shared__ bf16_t Vts[128 * 64];  // [d][key] for this tile
    const int tid = threadIdx.x;
    const int wave = tid >> 6, lane = tid & 63;
    const int quad = lane >> 4, l16 = lane & 15;
    const int QKLD = 4096, T = 4096, S = 2048, HIDO = 2048;
    const float SL2E = 0.088388347688f * 1.44269504089f;  // log2(e)/sqrt(128)

    const int qrow0 = blockIdx.z * S + blockIdx.x * 64;
    const int krow0 = blockIdx.z * S;
    const int hoff = blockIdx.y * 128;
    const int sw = l16 & 7;

    // Q fragments (B-operand, n = q = l16 within this wave's 16 q-rows)
    bf16x8 qf[4];
    const bf16_t* qptr = Qp + (size_t)(qrow0 + wave * 16 + l16) * QKLD + hoff;
#pragma unroll
    for (int ks = 0; ks < 4; ++ks) qf[ks] = *(const bf16x8*)(qptr + ks * 32 + quad * 8);

    float m_i = -3.0e38f, l_i = 0.f;   // stats for q = qrow0 + wave*16 + l16 (x4 replicated)
    floatx4 Oacc[8];
#pragma unroll
    for (int dt = 0; dt < 8; ++dt) Oacc[dt] = floatx4{0.f, 0.f, 0.f, 0.f};

    for (int kt = 0; kt < 32; ++kt) {
        int kb = krow0 + kt * 64;
        // K tile 64 keys x 128 d, source-swizzled within each 128B half-row
#pragma unroll
        for (int it = 0; it < 4; ++it) {
            int chunk = it * 256 + tid;
            int r = chunk >> 4, c = chunk & 15;
            int c2 = c ^ (r & 7);
            async16(Kp + (size_t)(kb + r) * QKLD + hoff + c2 * 8,
                    Ks + (it * 256 + wave * 64) * 8);
        }
        // Vt tile 128 d x 64 keys
#pragma unroll
        for (int it = 0; it < 4; ++it) {
            int chunk = it * 256 + tid;
            int r = chunk >> 3, c = chunk & 7;
            int c2 = c ^ (r & 7);
            async16(Vt + (size_t)(hoff + r) * T + kb + c2 * 8,
                    Vts + (it * 256 + wave * 64) * 8);
        }
        __syncthreads();

        // S^T = K Q^T : D[m=key(nt*16+quad*4+r)][n=q=l16]
        floatx4 sf[4];
#pragma unroll
        for (int nt = 0; nt < 4; ++nt) sf[nt] = floatx4{0.f, 0.f, 0.f, 0.f};
#pragma unroll
        for (int ks = 0; ks < 4; ++ks) {
#pragma unroll
            for (int nt = 0; nt < 4; ++nt) {
                bf16x8 a = *(const bf16x8*)(Ks + (nt * 16 + l16) * 128 +
                                            ((ks * 4 + quad) ^ sw) * 8);
                sf[nt] = __builtin_amdgcn_mfma_f32_16x16x32_bf16(a, qf[ks], sf[nt], 0, 0, 0);
            }
        }

        // online softmax in log2 domain; lane holds 16 keys of q-row l16
        float mx = -3.0e38f;
#pragma unroll
        for (int nt = 0; nt < 4; ++nt)
#pragma unroll
            for (int r = 0; r < 4; ++r) mx = fmaxf(mx, sf[nt][r]);
        mx *= SL2E;
        mx = fmaxf(mx, __shfl_xor(mx, 16));
        mx = fmaxf(mx, __shfl_xor(mx, 32));
        float mnew = fmaxf(m_i, mx);
        float alpha = exp2f(m_i - mnew);
        m_i = mnew;

        float rsum = 0.f;
        uint32_t pk[8];  // pk[nt*2+h] = bf16 pair (r=2h, r=2h+1)
#pragma unroll
        for (int nt = 0; nt < 4; ++nt)
#pragma unroll
            for (int h = 0; h < 2; ++h) {
                float p0 = exp2f(sf[nt][2 * h] * SL2E - mnew);
                float p1 = exp2f(sf[nt][2 * h + 1] * SL2E - mnew);
                rsum += p0 + p1;
                pk[nt * 2 + h] = pack2(p0, p1);
            }
        rsum += __shfl_xor(rsum, 16);
        rsum += __shfl_xor(rsum, 32);
        l_i = l_i * alpha + rsum;

        // rescale O (rows m = quad*4+r; stats live at lane l16 = that row)
        float aO[4];
#pragma unroll
        for (int r = 0; r < 4; ++r) aO[r] = __shfl(alpha, quad * 4 + r);
#pragma unroll
        for (int dt = 0; dt < 8; ++dt)
#pragma unroll
            for (int r = 0; r < 4; ++r) Oacc[dt][r] *= aO[r];

        // PV: A-frag[j] = P[q=l16][key=ks2*32+quad*8+j], gathered from the two
        // source quads holding those keys (same l16 column) via shuffles.
        const int qsel = quad >> 1;
        const int src0 = (quad & 1) * 32 + l16;
        const int src1 = src0 + 16;
#pragma unroll
        for (int ks2 = 0; ks2 < 2; ++ks2) {
            const int rA = 4 * ks2;
            uint32_t a0 = (uint32_t)__shfl((int)pk[rA + 0], src0);
            uint32_t b0 = (uint32_t)__shfl((int)pk[rA + 2], src0);
            uint32_t a1 = (uint32_t)__shfl((int)pk[rA + 1], src0);
            uint32_t b1 = (uint32_t)__shfl((int)pk[rA + 3], src0);
            uint32_t a2 = (uint32_t)__shfl((int)pk[rA + 0], src1);
            uint32_t b2 = (uint32_t)__shfl((int)pk[rA + 2], src1);
            uint32_t a3 = (uint32_t)__shfl((int)pk[rA + 1], src1);
            uint32_t b3 = (uint32_t)__shfl((int)pk[rA + 3], src1);
            union { uint32_t u[4]; bf16x8 v; } af;
            af.u[0] = qsel ? b0 : a0;
            af.u[1] = qsel ? b1 : a1;
            af.u[2] = qsel ? b2 : a2;
            af.u[3] = qsel ? b3 : a3;
#pragma unroll
            for (int dt = 0; dt < 8; ++dt) {
                bf16x8 b = *(const bf16x8*)(Vts + (dt * 16 + l16) * 64 +
                                            ((ks2 * 4 + quad) ^ sw) * 8);
                Oacc[dt] = __builtin_amdgcn_mfma_f32_16x16x32_bf16(af.v, b, Oacc[dt], 0, 0, 0);
            }
        }
        __syncthreads();  // protect Ks/Vts before next restage
    }
    // epilogue: O / l  (O rows m = quad*4+r)
    float linv = 1.0f / l_i;
    float lO[4];
#pragma unroll
    for (int r = 0; r < 4; ++r) lO[r] = __shfl(linv, quad * 4 + r);
#pragma unroll
    for (int dt = 0; dt < 8; ++dt)
#pragma unroll
        for (int r = 0; r < 4; ++r) {
            int row = qrow0 + wave * 16 + quad * 4 + r;
            int col = hoff + dt * 16 + l16;
            O[(size_t)row * HIDO + col] = (bf16_t)(Oacc[dt][r] * lO[r]);
        }
}

// ---------- launch ----------
extern "C" void kernel_launch(void* const* d_in, const int* in_sizes, int n_in,
                              void* d_out, int out_size, void* d_ws, size_t ws_size,
                              hipStream_t stream) {
    const float* x  = (const float*)d_in[0];
    const float* Wq = (const float*)d_in[1];
    const float* bq = (const float*)d_in[2];
    const float* Wk = (const float*)d_in[3];
    const float* bk = (const float*)d_in[4];
    const float* Wv = (const float*)d_in[5];
    const float* bv = (const float*)d_in[6];
    const float* Wo = (const float*)d_in[7];
    const float* bo = (const float*)d_in[8];
    float* out = (float*)d_out;

    const int T = 4096;          // B*S tokens
    const int H = 2048;          // hidden
    bf16_t* ws  = (bf16_t*)d_ws;
    bf16_t* xb  = ws;                         // T*H
    bf16_t* wqb = xb  + (size_t)T * H;        // H*H  (Wq; Wk must follow contiguously)
    bf16_t* wkb = wqb + (size_t)H * H;
    bf16_t* wvb = wkb + (size_t)H * H;
    bf16_t* wob = wvb + (size_t)H * H;
    bf16_t* QKb = wob + (size_t)H * H;        // T x 4096 (cols 0..2047=Q, 2048..4095=K)
    bf16_t* Vtb = QKb + (size_t)T * 2 * H;    // H x T  (V transposed: feature-major)
    bf16_t* Ab  = Vtb + (size_t)H * T;        // T*H attention context
    size_t need = (size_t)(Ab + (size_t)T * H - ws) * sizeof(bf16_t);
    if (ws_size < need) return;

    cvt_f32_bf16<<<T * H / 2048, 256, 0, stream>>>(x, xb);
    cvt_f32_bf16<<<H * H / 2048, 256, 0, stream>>>(Wq, wqb);
    cvt_f32_bf16<<<H * H / 2048, 256, 0, stream>>>(Wk, wkb);
    cvt_f32_bf16<<<H * H / 2048, 256, 0, stream>>>(Wv, wvb);
    cvt_f32_bf16<<<H * H / 2048, 256, 0, stream>>>(Wo, wob);

    // merged Q|K projection: B = [Wq;Wk] (4096 x 2048), split col bias, ldc=4096
    dim3 gqk(T / 128, 4096 / 128);  // (32,32) = 1024 blocks, full grid fill
    gemm_bt<false, false><<<gqk, 256, 0, stream>>>(xb, wqb, bq, bk, H,
                                                   nullptr, QKb, T, 4096, H, 4096);
    // V^T = Wv * x^T : swap operands, bias per row (feature), ldc = T
    dim3 gv(H / 128, T / 128);      // (16,32)
    gemm_bt<false, true><<<gv, 256, 0, stream>>>(wvb, xb, bv, nullptr, 0,
                                                 nullptr, Vtb, H, T, H, T);

    flash_attn<<<dim3(32, 16, 2), 256, 0, stream>>>(QKb, QKb + H, Vtb, Ab);

    dim3 go(T / 128, H / 128);      // (32,16)
    gemm_bt<true, false><<<go, 256, 0, stream>>>(Ab, wob, bo, nullptr, H,
                                                 out, nullptr, T, H, H, H);
}